// Round 2
// baseline (2742.825 us; speedup 1.0000x reference)
//
#include <hip/hip_runtime.h>
#include <math.h>

// Problem constants
#define Nn     2048
#define NEc    32768
#define ETc    4
#define NEDGE  (ETc * NEc)     // 131072
#define FS     68              // padded feature stride (66 used)
#define HIDc   128
#define GSZ    512             // 4*HID

typedef float f4 __attribute__((ext_vector_type(4)));

// ---------------- workspace layout (offsets in 4-byte units) ----------------
#define O_COEFF   0L
#define O_COUNTS  (O_COEFF  + 32L)
#define O_OFFS    (O_COUNTS + 2048L)
#define O_CURSOR  (O_OFFS   + 2052L)
#define O_PACKED  (O_CURSOR + 2048L)
#define O_VALS    (O_PACKED + 131072L)
#define O_U       (O_VALS   + 131072L)              // 2048*68
#define O_V       (O_U      + 139264L)              // 2 ch * 2048*68
#define O_T       (O_V      + 278528L)
#define O_S       (O_T      + 278528L)
#define O_X       (O_S      + 278528L)              // 2048*128
#define O_G       (O_X      + 262144L)              // 2048*512
#define O_HS      (O_G      + 1048576L)             // 2048*128

// ---- softmax coefficients: coeff[(l*2+c)*4 + e] = softmax(gt_w[l][c][:])[e]
__global__ void coeff_kernel(const float* __restrict__ gtw, float* __restrict__ coeff) {
    int t = threadIdx.x;
    if (t < 6) {
        const float* w = gtw + t * 4;
        float m = fmaxf(fmaxf(w[0], w[1]), fmaxf(w[2], w[3]));
        float e0 = expf(w[0] - m), e1 = expf(w[1] - m);
        float e2 = expf(w[2] - m), e3 = expf(w[3] - m);
        float s = ((e0 + e1) + e2) + e3;
        float r = 1.0f / s;
        coeff[t * 4 + 0] = e0 * r;
        coeff[t * 4 + 1] = e1 * r;
        coeff[t * 4 + 2] = e2 * r;
        coeff[t * 4 + 3] = e3 * r;
    }
}

// ---- CSR build: count per row
__global__ void count_kernel(const int* __restrict__ ei, int* __restrict__ counts) {
    int e = blockIdx.x * 256 + threadIdx.x;          // 0..131071
    int t = e >> 15, k = e & 32767;
    int row = ei[t * 65536 + k];
    atomicAdd(&counts[row], 1);
}

// ---- exclusive scan over 2048 counts (single block, Hillis-Steele)
__global__ __launch_bounds__(1024) void scan_kernel(const int* __restrict__ counts,
                                                    int* __restrict__ offs,
                                                    int* __restrict__ cursor) {
    __shared__ int buf[2][2048];
    int t = threadIdx.x;
    buf[0][t]        = counts[t];
    buf[0][t + 1024] = counts[t + 1024];
    __syncthreads();
    int p = 0;
    for (int off = 1; off < 2048; off <<= 1) {
        for (int i = t; i < 2048; i += 1024) {
            int v = buf[p][i];
            if (i >= off) v += buf[p][i - off];
            buf[p ^ 1][i] = v;
        }
        __syncthreads();
        p ^= 1;
    }
    for (int i = t; i < 2048; i += 1024) {
        int inc = buf[p][i];
        offs[i + 1] = inc;
        int ex = inc - counts[i];
        cursor[i] = ex;
    }
    if (t == 0) offs[0] = 0;
}

// ---- scatter edges into CSR slots (etype packed in high bits of col word)
__global__ void scatter_kernel(const int* __restrict__ ei, const float* __restrict__ ev,
                               int* __restrict__ cursor, int* __restrict__ packed,
                               float* __restrict__ vals) {
    int e = blockIdx.x * 256 + threadIdx.x;
    int t = e >> 15, k = e & 32767;
    int row = ei[t * 65536 + k];
    int col = ei[t * 65536 + 32768 + k];
    float v = ev[t * 32768 + k];
    int slot = atomicAdd(&cursor[row], 1);
    packed[slot] = col | (t << 16);
    vals[slot] = v;
}

// ---- XW = X @ W_gcn, assemble U = [XW | 1 | 0 | pad]
__global__ void xw_kernel(const float* __restrict__ X, const float* __restrict__ Wg,
                          float* __restrict__ U) {
    __shared__ float Wl[64][65];
    __shared__ float Xl[16][64];
    int tid = threadIdx.x;                            // 256 threads
    for (int i = tid; i < 4096; i += 256) Wl[i >> 6][i & 63] = Wg[i];
    int r0 = blockIdx.x * 16;
    for (int i = tid; i < 1024; i += 256) Xl[i >> 6][i & 63] = X[r0 * 64 + i];
    __syncthreads();
    int lane = tid & 63, wv = tid >> 6;
    for (int rr = wv; rr < 16; rr += 4) {
        float acc = 0.0f;
        #pragma unroll
        for (int k = 0; k < 64; ++k) acc += Xl[rr][k] * Wl[k][lane];
        long r = r0 + rr;
        U[r * FS + lane] = acc;
        if (lane == 0) {
            U[r * FS + 64] = 1.0f;   // ones column (carries deg chains)
            U[r * FS + 65] = 0.0f;
            U[r * FS + 66] = 0.0f;
            U[r * FS + 67] = 0.0f;
        }
    }
}

// ---- SpMM: out_c[row, :] = sum_e coeff[layer][c][etype]*val * in_c[col, :]
__global__ __launch_bounds__(64) void spmm_kernel(
    const int* __restrict__ offs, const int* __restrict__ packed,
    const float* __restrict__ vals, const float* __restrict__ coeff, int layer,
    const float* __restrict__ in, long in_ch_stride,
    float* __restrict__ out, long out_ch_stride, int append_one) {
    __shared__ float cl[4];
    int c = blockIdx.y;
    int lane = threadIdx.x;
    if (lane < 4) cl[lane] = coeff[(layer * 2 + c) * 4 + lane];
    __syncthreads();
    int row = blockIdx.x;
    const float* inc = in + (long)c * in_ch_stride;
    float* outc = out + (long)c * out_ch_stride;
    int s = offs[row], e = offs[row + 1];
    float acc = 0.0f, accb = 0.0f;
    for (int i = s; i < e; ++i) {
        int pc = packed[i];
        float v = vals[i];
        long col = pc & 0xFFFF;
        float w = cl[pc >> 16] * v;
        acc += w * inc[col * FS + lane];
        if (lane < 2) accb += w * inc[col * FS + 64 + lane];
    }
    outc[(long)row * FS + lane] = acc;
    if (lane < 2) {
        float vb = accb;
        if (append_one && lane == 1) vb = 1.0f;       // append constant-1 column
        outc[(long)row * FS + 64 + lane] = vb;
    }
}

// ---- finalize: X_[n, c*64+f] = relu(dinv2*dinv1*S_c[n,f] + b_gcn[f])
__global__ __launch_bounds__(128) void finalize_kernel(const float* __restrict__ S,
                                                       const float* __restrict__ bg,
                                                       float* __restrict__ Xo) {
    int n = blockIdx.x;
    int tid = threadIdx.x;                            // 128
    int c = tid >> 6, f = tid & 63;
    const float* Sc = S + (long)c * 139264L + (long)n * FS;
    float deg1 = Sc[65];
    float dinv1 = (deg1 != 0.0f) ? 1.0f / deg1 : 0.0f;
    float deg2 = dinv1 * Sc[64];
    float dinv2 = (deg2 != 0.0f) ? 1.0f / deg2 : 0.0f;
    float v = dinv2 * (dinv1 * Sc[f]) + bg[f];
    Xo[(long)n * 128 + tid] = v > 0.0f ? v : 0.0f;
}

// ---- G[n, g] = X_[n,:] . W_ih[g,:] + b_ih[g] + b_hh[g]
__global__ __launch_bounds__(512) void gin_kernel(const float* __restrict__ Xi,
                                                  const float* __restrict__ Wih,
                                                  const float* __restrict__ bih,
                                                  const float* __restrict__ bhh,
                                                  float* __restrict__ G) {
    __shared__ float Xl[16][128];
    int tid = threadIdx.x;                            // 512; g = tid
    int r0 = blockIdx.x * 16;
    for (int i = tid; i < 2048; i += 512) Xl[i >> 7][i & 127] = Xi[(long)r0 * 128 + i];
    __syncthreads();
    float acc[16];
    #pragma unroll
    for (int r = 0; r < 16; ++r) acc[r] = 0.0f;
    for (int k = 0; k < 128; ++k) {
        float w = Wih[(long)tid * 128 + k];
        #pragma unroll
        for (int r = 0; r < 16; ++r) acc[r] += Xl[r][k] * w;
    }
    float b = bih[tid] + bhh[tid];
    #pragma unroll
    for (int r = 0; r < 16; ++r) G[(long)(r0 + r) * GSZ + tid] = acc[r] + b;
}

// ---- sequential LSTM: one block, 1024 threads (16 waves).
// Thread map: wave w(0..15), lane l(0..63): gate q=l>>4, unit j=w*8+(l&7),
// half=(l>>3)&1 -> thread owns 64-wide half-dot of W_hh row q*128+j.
// Combine: shfl_xor(8) joins halves; 4 bpermutes gather the gates; every lane
// redundantly updates c,h for its unit. h double-buffered in LDS; ONE barrier/step.
__global__ __launch_bounds__(1024, 4) void lstm_kernel(const float* __restrict__ Whh,
                                                       const float* __restrict__ G,
                                                       float* __restrict__ hs) {
    __shared__ float h2[2][128];
    int tid = threadIdx.x;
    int w = tid >> 6, l = tid & 63;
    int q = l >> 4, b = l & 7, half = (l >> 3) & 1;
    int j = w * 8 + b;
    int row = q * 128 + j;

    // activation constants: gate q==2 (g) uses tanh = 2*sigmoid(2x)-1
    float m1 = (q == 2) ? 2.0f : 1.0f;
    float m2 = (q == 2) ? -1.0f : 0.0f;

    const f4* W4 = reinterpret_cast<const f4*>(Whh) + (long)row * 32 + half * 16;
    f4 w0 = W4[0],  w1 = W4[1],  w2 = W4[2],  w3 = W4[3];
    f4 w4 = W4[4],  w5 = W4[5],  w6 = W4[6],  w7 = W4[7];
    f4 w8 = W4[8],  w9 = W4[9],  w10 = W4[10], w11 = W4[11];
    f4 w12 = W4[12], w13 = W4[13], w14 = W4[14], w15 = W4[15];
    // pin weights in VGPRs: forbid rematerialization/reload inside the t-loop
    asm volatile("" : "+v"(w0), "+v"(w1), "+v"(w2), "+v"(w3),
                      "+v"(w4), "+v"(w5), "+v"(w6), "+v"(w7),
                      "+v"(w8), "+v"(w9), "+v"(w10), "+v"(w11),
                      "+v"(w12), "+v"(w13), "+v"(w14), "+v"(w15));

    if (tid < 128) h2[0][tid] = 0.0f;
    float c = 0.0f;
    float gcur = G[row];
    __syncthreads();

    for (int t = 0; t < Nn; ++t) {
        float gnext = (t + 1 < Nn) ? G[(long)(t + 1) * GSZ + row] : 0.0f;
        const f4* hb = reinterpret_cast<const f4*>(&h2[t & 1][half * 64]);
        float a0 = 0.0f, a1 = 0.0f, a2 = 0.0f, a3 = 0.0f;
        #define DOT(i, wi) { f4 hv = hb[i]; \
            a0 = fmaf(wi.x, hv.x, a0); a1 = fmaf(wi.y, hv.y, a1); \
            a2 = fmaf(wi.z, hv.z, a2); a3 = fmaf(wi.w, hv.w, a3); }
        DOT(0, w0)   DOT(1, w1)   DOT(2, w2)   DOT(3, w3)
        DOT(4, w4)   DOT(5, w5)   DOT(6, w6)   DOT(7, w7)
        DOT(8, w8)   DOT(9, w9)   DOT(10, w10) DOT(11, w11)
        DOT(12, w12) DOT(13, w13) DOT(14, w14) DOT(15, w15)
        #undef DOT
        float a = (a0 + a1) + (a2 + a3);
        a += __shfl_xor(a, 8);
        a += gcur;
        // activation: sigmoid(m1*a)*m1 + m2  (== tanh(a) when q==2)
        float e = __expf(-a * m1);
        float s = __builtin_amdgcn_rcpf(1.0f + e);
        float av = fmaf(s, m1, m2);
        // gather the 4 gates of unit j (act copies live at lanes q'*16+b)
        float iv = __shfl(av, b);
        float fv = __shfl(av, 16 + b);
        float gv = __shfl(av, 32 + b);
        float ov = __shfl(av, 48 + b);
        c = fmaf(fv, c, iv * gv);
        float e2 = __expf(-2.0f * c);
        float th = fmaf(2.0f, __builtin_amdgcn_rcpf(1.0f + e2), -1.0f);
        float h = ov * th;
        if (l < 8) {                        // l<8 -> q=0, half=0, b=l, j=w*8+l
            h2[(t + 1) & 1][j] = h;
            hs[(long)t * HIDc + j] = h;
        }
        gcur = gnext;
        __syncthreads();
    }
}

// ---- y[n] = leaky_relu(hs[n,:] . W_lin + b_lin)
__global__ __launch_bounds__(256) void y_kernel(const float* __restrict__ hs,
                                                const float* __restrict__ wl,
                                                const float* __restrict__ bl,
                                                float* __restrict__ out) {
    int row = blockIdx.x * 4 + (threadIdx.x >> 6);
    int lane = threadIdx.x & 63;
    float p = hs[(long)row * 128 + lane] * wl[lane] +
              hs[(long)row * 128 + 64 + lane] * wl[64 + lane];
    #pragma unroll
    for (int off = 32; off > 0; off >>= 1) p += __shfl_down(p, off);
    if (lane == 0) {
        float y = p + bl[0];
        out[row] = (y >= 0.0f) ? y : 0.2f * y;
    }
}

extern "C" void kernel_launch(void* const* d_in, const int* in_sizes, int n_in,
                              void* d_out, int out_size, void* d_ws, size_t ws_size,
                              hipStream_t stream) {
    (void)in_sizes; (void)n_in; (void)out_size; (void)ws_size;
    const int*   ei   = (const int*)  d_in[0];   // (4,2,32768)
    const float* ev   = (const float*)d_in[1];   // (4,32768)
    const float* X    = (const float*)d_in[2];   // (2048,64)
    const float* gtw  = (const float*)d_in[4];   // (3,2,4)
    const float* Wg   = (const float*)d_in[5];   // (64,64)
    const float* bg   = (const float*)d_in[6];   // (64)
    const float* Wih  = (const float*)d_in[7];   // (512,128)
    const float* Whh  = (const float*)d_in[8];   // (512,128)
    const float* bih  = (const float*)d_in[9];
    const float* bhh  = (const float*)d_in[10];
    const float* wl   = (const float*)d_in[11];  // (1,128)
    const float* bl   = (const float*)d_in[12];
    float* out = (float*)d_out;

    float* ws = (float*)d_ws;
    float* coeff  = ws + O_COEFF;
    int*   counts = (int*)(ws + O_COUNTS);
    int*   offs   = (int*)(ws + O_OFFS);
    int*   cursor = (int*)(ws + O_CURSOR);
    int*   packed = (int*)(ws + O_PACKED);
    float* vals   = ws + O_VALS;
    float* U      = ws + O_U;
    float* V      = ws + O_V;
    float* T      = ws + O_T;
    float* S      = ws + O_S;
    float* Xf     = ws + O_X;
    float* G      = ws + O_G;
    float* hsb    = ws + O_HS;

    hipMemsetAsync(counts, 0, 2048 * sizeof(int), stream);
    coeff_kernel<<<1, 64, 0, stream>>>(gtw, coeff);
    count_kernel<<<NEDGE / 256, 256, 0, stream>>>(ei, counts);
    scan_kernel<<<1, 1024, 0, stream>>>(counts, offs, cursor);
    scatter_kernel<<<NEDGE / 256, 256, 0, stream>>>(ei, ev, cursor, packed, vals);
    xw_kernel<<<Nn / 16, 256, 0, stream>>>(X, Wg, U);
    spmm_kernel<<<dim3(Nn, 2), 64, 0, stream>>>(offs, packed, vals, coeff, 2,
                                                U, 0L, V, 139264L, 1);
    spmm_kernel<<<dim3(Nn, 2), 64, 0, stream>>>(offs, packed, vals, coeff, 1,
                                                V, 139264L, T, 139264L, 0);
    spmm_kernel<<<dim3(Nn, 2), 64, 0, stream>>>(offs, packed, vals, coeff, 0,
                                                T, 139264L, S, 139264L, 0);
    finalize_kernel<<<Nn, 128, 0, stream>>>(S, bg, Xf);
    gin_kernel<<<Nn / 16, 512, 0, stream>>>(Xf, Wih, bih, bhh, G);
    lstm_kernel<<<1, 1024, 0, stream>>>(Whh, G, hsb);
    y_kernel<<<Nn / 4, 256, 0, stream>>>(hsb, wl, bl, out);
}

// Round 3
// 1723.242 us; speedup vs baseline: 1.5917x; 1.5917x over previous
//
#include <hip/hip_runtime.h>
#include <math.h>

// Problem constants
#define Nn     2048
#define NEc    32768
#define ETc    4
#define NEDGE  (ETc * NEc)     // 131072
#define FS     68              // padded feature stride (66 used)
#define HIDc   128
#define GSZ    512             // 4*HID

typedef float f4 __attribute__((ext_vector_type(4)));

// ---------------- workspace layout (offsets in 4-byte units) ----------------
#define O_COEFF   0L
#define O_COUNTS  (O_COEFF  + 32L)
#define O_OFFS    (O_COUNTS + 2048L)
#define O_CURSOR  (O_OFFS   + 2052L)
#define O_PACKED  (O_CURSOR + 2048L)
#define O_WVAL    (O_PACKED + 131072L)              // 6 * 131072
#define O_U       (O_WVAL   + 786432L)              // 2048*68
#define O_V       (O_U      + 139264L)              // 2 ch * 2048*68
#define O_T       (O_V      + 278528L)
#define O_S       (O_T      + 278528L)
#define O_X       (O_S      + 278528L)              // 2048*128
#define O_G       (O_X      + 262144L)              // 2048*512
#define O_HS      (O_G      + 1048576L)             // 2048*128
// total ~3.4M floats = ~13.8 MB

// ---- softmax coefficients: coeff[(l*2+c)*4 + e] = softmax(gt_w[l][c][:])[e]
__global__ void coeff_kernel(const float* __restrict__ gtw, float* __restrict__ coeff) {
    int t = threadIdx.x;
    if (t < 6) {
        const float* w = gtw + t * 4;
        float m = fmaxf(fmaxf(w[0], w[1]), fmaxf(w[2], w[3]));
        float e0 = expf(w[0] - m), e1 = expf(w[1] - m);
        float e2 = expf(w[2] - m), e3 = expf(w[3] - m);
        float s = ((e0 + e1) + e2) + e3;
        float r = 1.0f / s;
        coeff[t * 4 + 0] = e0 * r;
        coeff[t * 4 + 1] = e1 * r;
        coeff[t * 4 + 2] = e2 * r;
        coeff[t * 4 + 3] = e3 * r;
    }
}

// ---- CSR build: count per row
__global__ void count_kernel(const int* __restrict__ ei, int* __restrict__ counts) {
    int e = blockIdx.x * 256 + threadIdx.x;          // 0..131071
    int t = e >> 15, k = e & 32767;
    int row = ei[t * 65536 + k];
    atomicAdd(&counts[row], 1);
}

// ---- exclusive scan over 2048 counts (single block, Hillis-Steele)
__global__ __launch_bounds__(1024) void scan_kernel(const int* __restrict__ counts,
                                                    int* __restrict__ offs,
                                                    int* __restrict__ cursor) {
    __shared__ int buf[2][2048];
    int t = threadIdx.x;
    buf[0][t]        = counts[t];
    buf[0][t + 1024] = counts[t + 1024];
    __syncthreads();
    int p = 0;
    for (int off = 1; off < 2048; off <<= 1) {
        for (int i = t; i < 2048; i += 1024) {
            int v = buf[p][i];
            if (i >= off) v += buf[p][i - off];
            buf[p ^ 1][i] = v;
        }
        __syncthreads();
        p ^= 1;
    }
    for (int i = t; i < 2048; i += 1024) {
        int inc = buf[p][i];
        offs[i + 1] = inc;
        int ex = inc - counts[i];
        cursor[i] = ex;
    }
    if (t == 0) offs[0] = 0;
}

// ---- scatter edges into CSR slots; pre-multiply the 6 layer/channel coeffs
__global__ void scatter_kernel(const int* __restrict__ ei, const float* __restrict__ ev,
                               const float* __restrict__ coeff,
                               int* __restrict__ cursor, int* __restrict__ packed,
                               float* __restrict__ wvals) {
    int e = blockIdx.x * 256 + threadIdx.x;
    int t = e >> 15, k = e & 32767;
    int row = ei[t * 65536 + k];
    int col = ei[t * 65536 + 32768 + k];
    float v = ev[t * 32768 + k];
    int slot = atomicAdd(&cursor[row], 1);
    packed[slot] = col;
    #pragma unroll
    for (int lc = 0; lc < 6; ++lc)
        wvals[lc * 131072L + slot] = coeff[lc * 4 + t] * v;
}

// ---- XW = X @ W_gcn, assemble U = [XW | 1 | 0 | pad]
__global__ void xw_kernel(const float* __restrict__ X, const float* __restrict__ Wg,
                          float* __restrict__ U) {
    __shared__ float Wl[64][65];
    __shared__ float Xl[16][64];
    int tid = threadIdx.x;                            // 256 threads
    for (int i = tid; i < 4096; i += 256) Wl[i >> 6][i & 63] = Wg[i];
    int r0 = blockIdx.x * 16;
    for (int i = tid; i < 1024; i += 256) Xl[i >> 6][i & 63] = X[r0 * 64 + i];
    __syncthreads();
    int lane = tid & 63, wv = tid >> 6;
    for (int rr = wv; rr < 16; rr += 4) {
        float acc = 0.0f;
        #pragma unroll
        for (int k = 0; k < 64; ++k) acc += Xl[rr][k] * Wl[k][lane];
        long r = r0 + rr;
        U[r * FS + lane] = acc;
        if (lane == 0) {
            U[r * FS + 64] = 1.0f;   // ones column (carries deg chains)
            U[r * FS + 65] = 0.0f;
            U[r * FS + 66] = 0.0f;
            U[r * FS + 67] = 0.0f;
        }
    }
}

// ---- SpMM, both channels fused: out_c[row,:] = sum_i wv_c[i] * in_c[col_i,:]
__global__ __launch_bounds__(64) void spmm_kernel(
    const int* __restrict__ offs, const int* __restrict__ packed,
    const float* __restrict__ wvals, int layer,
    const float* __restrict__ in, long in_ch_stride,
    float* __restrict__ out, long out_ch_stride, int append_one) {
    int lane = threadIdx.x;
    int row = blockIdx.x;
    const float* wv0 = wvals + (layer * 2 + 0) * 131072L;
    const float* wv1 = wvals + (layer * 2 + 1) * 131072L;
    const float* in0 = in;
    const float* in1 = in + in_ch_stride;            // == in0 when stride 0
    int s = offs[row], e = offs[row + 1];
    float acc0 = 0.0f, acc1 = 0.0f, accb0 = 0.0f, accb1 = 0.0f;
    for (int i = s; i < e; ++i) {
        long col = packed[i];
        float w0 = wv0[i], w1 = wv1[i];
        float x0 = in0[col * FS + lane];
        float x1 = in1[col * FS + lane];
        acc0 = fmaf(w0, x0, acc0);
        acc1 = fmaf(w1, x1, acc1);
        if (lane < 2) {
            accb0 = fmaf(w0, in0[col * FS + 64 + lane], accb0);
            accb1 = fmaf(w1, in1[col * FS + 64 + lane], accb1);
        }
    }
    out[(long)row * FS + lane] = acc0;
    out[out_ch_stride + (long)row * FS + lane] = acc1;
    if (lane < 2) {
        float vb0 = accb0, vb1 = accb1;
        if (append_one && lane == 1) { vb0 = 1.0f; vb1 = 1.0f; }
        out[(long)row * FS + 64 + lane] = vb0;
        out[out_ch_stride + (long)row * FS + 64 + lane] = vb1;
    }
}

// ---- finalize: X_[n, c*64+f] = relu(dinv2*dinv1*S_c[n,f] + b_gcn[f])
__global__ __launch_bounds__(128) void finalize_kernel(const float* __restrict__ S,
                                                       const float* __restrict__ bg,
                                                       float* __restrict__ Xo) {
    int n = blockIdx.x;
    int tid = threadIdx.x;                            // 128
    int c = tid >> 6, f = tid & 63;
    const float* Sc = S + (long)c * 139264L + (long)n * FS;
    float deg1 = Sc[65];
    float dinv1 = (deg1 != 0.0f) ? 1.0f / deg1 : 0.0f;
    float deg2 = dinv1 * Sc[64];
    float dinv2 = (deg2 != 0.0f) ? 1.0f / deg2 : 0.0f;
    float v = dinv2 * (dinv1 * Sc[f]) + bg[f];
    Xo[(long)n * 128 + tid] = v > 0.0f ? v : 0.0f;
}

// ---- G[n, g] = X_[n,:] . W_ih[g,:] + b_ih[g] + b_hh[g]
__global__ __launch_bounds__(512) void gin_kernel(const float* __restrict__ Xi,
                                                  const float* __restrict__ Wih,
                                                  const float* __restrict__ bih,
                                                  const float* __restrict__ bhh,
                                                  float* __restrict__ G) {
    __shared__ float Xl[16][128];
    int tid = threadIdx.x;                            // 512; g = tid
    int r0 = blockIdx.x * 16;
    for (int i = tid; i < 2048; i += 512) Xl[i >> 7][i & 127] = Xi[(long)r0 * 128 + i];
    __syncthreads();
    float acc[16];
    #pragma unroll
    for (int r = 0; r < 16; ++r) acc[r] = 0.0f;
    for (int k = 0; k < 128; ++k) {
        float w = Wih[(long)tid * 128 + k];
        #pragma unroll
        for (int r = 0; r < 16; ++r) acc[r] += Xl[r][k] * w;
    }
    float b = bih[tid] + bhh[tid];
    #pragma unroll
    for (int r = 0; r < 16; ++r) G[(long)(r0 + r) * GSZ + tid] = acc[r] + b;
}

// ---- sequential LSTM: one block, 512 threads (8 waves), one output row each.
// Lane map: wave w(0..7), lane l(0..63): gate q=l>>4, sub=l&15, unit j=w*16+sub,
// W_hh row = q*128+j. All lanes read full h (wave-uniform broadcast b128 from
// LDS, conflict-free). Gate mixing via 4 in-wave shfls; every lane keeps its
// unit's c redundantly. h double-buffered in LDS -> ONE barrier per step.
// Weights pinned in VGPRs by an IN-LOOP asm tie (loop-carried -> unspillable).
__global__ __launch_bounds__(512, 2) void lstm_kernel(const float* __restrict__ Whh,
                                                      const float* __restrict__ G,
                                                      float* __restrict__ hs) {
    __shared__ float h2[2][128];
    int tid = threadIdx.x;
    int w = tid >> 6, l = tid & 63;
    int q = l >> 4, sub = l & 15;
    int j = w * 16 + sub;                 // hidden unit 0..127
    int row = q * 128 + j;                // W_hh / G row

    // activation constants: gate q==2 (g) uses tanh = 2*sigmoid(2x)-1
    float m1 = (q == 2) ? 2.0f : 1.0f;
    float m2 = (q == 2) ? -1.0f : 0.0f;

    const f4* W4 = reinterpret_cast<const f4*>(Whh) + (long)row * 32;
    f4 w0 = W4[0],  w1 = W4[1],  w2 = W4[2],  w3 = W4[3];
    f4 w4 = W4[4],  w5 = W4[5],  w6 = W4[6],  w7 = W4[7];
    f4 w8 = W4[8],  w9 = W4[9],  w10 = W4[10], w11 = W4[11];
    f4 w12 = W4[12], w13 = W4[13], w14 = W4[14], w15 = W4[15];
    f4 w16 = W4[16], w17 = W4[17], w18 = W4[18], w19 = W4[19];
    f4 w20 = W4[20], w21 = W4[21], w22 = W4[22], w23 = W4[23];
    f4 w24 = W4[24], w25 = W4[25], w26 = W4[26], w27 = W4[27];
    f4 w28 = W4[28], w29 = W4[29], w30 = W4[30], w31 = W4[31];

    if (tid < 128) h2[0][tid] = 0.0f;
    float c = 0.0f;
    float gcur = G[row];
    __syncthreads();

    for (int t = 0; t < Nn; ++t) {
        float gnext = (t + 1 < Nn) ? G[(long)(t + 1) * GSZ + row] : 0.0f;
        const f4* hb = reinterpret_cast<const f4*>(h2[t & 1]);
        float a0 = 0.0f, a1 = 0.0f, a2 = 0.0f, a3 = 0.0f;
        #define DOT(i, wi) { f4 hv = hb[i]; \
            a0 = fmaf(wi.x, hv.x, a0); a1 = fmaf(wi.y, hv.y, a1); \
            a2 = fmaf(wi.z, hv.z, a2); a3 = fmaf(wi.w, hv.w, a3); }
        DOT(0, w0)   DOT(1, w1)   DOT(2, w2)   DOT(3, w3)
        DOT(4, w4)   DOT(5, w5)   DOT(6, w6)   DOT(7, w7)
        DOT(8, w8)   DOT(9, w9)   DOT(10, w10) DOT(11, w11)
        DOT(12, w12) DOT(13, w13) DOT(14, w14) DOT(15, w15)
        DOT(16, w16) DOT(17, w17) DOT(18, w18) DOT(19, w19)
        DOT(20, w20) DOT(21, w21) DOT(22, w22) DOT(23, w23)
        DOT(24, w24) DOT(25, w25) DOT(26, w26) DOT(27, w27)
        DOT(28, w28) DOT(29, w29) DOT(30, w30) DOT(31, w31)
        #undef DOT
        float a = ((a0 + a1) + (a2 + a3)) + gcur;
        // activation: sigmoid(m1*a)*m1 + m2  (== tanh(a) when q==2)
        float e = __expf(-a * m1);
        float av = fmaf(__builtin_amdgcn_rcpf(1.0f + e), m1, m2);
        // gather the 4 gates of unit j (copies live at lanes q'*16+sub)
        float iv = __shfl(av, sub);
        float fv = __shfl(av, 16 + sub);
        float gv = __shfl(av, 32 + sub);
        float ov = __shfl(av, 48 + sub);
        c = fmaf(fv, c, iv * gv);
        float e2 = __expf(-2.0f * c);
        float th = fmaf(2.0f, __builtin_amdgcn_rcpf(1.0f + e2), -1.0f);
        float h = ov * th;
        if (q == 0) {                      // one writer per unit
            h2[(t + 1) & 1][j] = h;
            hs[(long)t * HIDc + j] = h;
        }
        gcur = gnext;
        // IN-LOOP pin: weights become loop-carried; spill/remat now costs a
        // per-iteration store+load, so the allocator must keep them resident.
        asm volatile("" : "+v"(w0), "+v"(w1), "+v"(w2), "+v"(w3),
                          "+v"(w4), "+v"(w5), "+v"(w6), "+v"(w7),
                          "+v"(w8), "+v"(w9), "+v"(w10), "+v"(w11),
                          "+v"(w12), "+v"(w13), "+v"(w14), "+v"(w15));
        asm volatile("" : "+v"(w16), "+v"(w17), "+v"(w18), "+v"(w19),
                          "+v"(w20), "+v"(w21), "+v"(w22), "+v"(w23),
                          "+v"(w24), "+v"(w25), "+v"(w26), "+v"(w27),
                          "+v"(w28), "+v"(w29), "+v"(w30), "+v"(w31));
        __syncthreads();
    }
}

// ---- y[n] = leaky_relu(hs[n,:] . W_lin + b_lin)
__global__ __launch_bounds__(256) void y_kernel(const float* __restrict__ hs,
                                                const float* __restrict__ wl,
                                                const float* __restrict__ bl,
                                                float* __restrict__ out) {
    int row = blockIdx.x * 4 + (threadIdx.x >> 6);
    int lane = threadIdx.x & 63;
    float p = hs[(long)row * 128 + lane] * wl[lane] +
              hs[(long)row * 128 + 64 + lane] * wl[64 + lane];
    #pragma unroll
    for (int off = 32; off > 0; off >>= 1) p += __shfl_down(p, off);
    if (lane == 0) {
        float y = p + bl[0];
        out[row] = (y >= 0.0f) ? y : 0.2f * y;
    }
}

extern "C" void kernel_launch(void* const* d_in, const int* in_sizes, int n_in,
                              void* d_out, int out_size, void* d_ws, size_t ws_size,
                              hipStream_t stream) {
    (void)in_sizes; (void)n_in; (void)out_size; (void)ws_size;
    const int*   ei   = (const int*)  d_in[0];   // (4,2,32768)
    const float* ev   = (const float*)d_in[1];   // (4,32768)
    const float* X    = (const float*)d_in[2];   // (2048,64)
    const float* gtw  = (const float*)d_in[4];   // (3,2,4)
    const float* Wg   = (const float*)d_in[5];   // (64,64)
    const float* bg   = (const float*)d_in[6];   // (64)
    const float* Wih  = (const float*)d_in[7];   // (512,128)
    const float* Whh  = (const float*)d_in[8];   // (512,128)
    const float* bih  = (const float*)d_in[9];
    const float* bhh  = (const float*)d_in[10];
    const float* wl   = (const float*)d_in[11];  // (1,128)
    const float* bl   = (const float*)d_in[12];
    float* out = (float*)d_out;

    float* ws = (float*)d_ws;
    float* coeff  = ws + O_COEFF;
    int*   counts = (int*)(ws + O_COUNTS);
    int*   offs   = (int*)(ws + O_OFFS);
    int*   cursor = (int*)(ws + O_CURSOR);
    int*   packed = (int*)(ws + O_PACKED);
    float* wvals  = ws + O_WVAL;
    float* U      = ws + O_U;
    float* V      = ws + O_V;
    float* T      = ws + O_T;
    float* S      = ws + O_S;
    float* Xf     = ws + O_X;
    float* G      = ws + O_G;
    float* hsb    = ws + O_HS;

    hipMemsetAsync(counts, 0, 2048 * sizeof(int), stream);
    coeff_kernel<<<1, 64, 0, stream>>>(gtw, coeff);
    count_kernel<<<NEDGE / 256, 256, 0, stream>>>(ei, counts);
    scan_kernel<<<1, 1024, 0, stream>>>(counts, offs, cursor);
    scatter_kernel<<<NEDGE / 256, 256, 0, stream>>>(ei, ev, coeff, cursor, packed, wvals);
    xw_kernel<<<Nn / 16, 256, 0, stream>>>(X, Wg, U);
    // chain: V = A2 [XW|1] (append 1-col); T = A1 V; S = A0 T
    spmm_kernel<<<Nn, 64, 0, stream>>>(offs, packed, wvals, 2, U, 0L, V, 139264L, 1);
    spmm_kernel<<<Nn, 64, 0, stream>>>(offs, packed, wvals, 1, V, 139264L, T, 139264L, 0);
    spmm_kernel<<<Nn, 64, 0, stream>>>(offs, packed, wvals, 0, T, 139264L, S, 139264L, 0);
    finalize_kernel<<<Nn, 128, 0, stream>>>(S, bg, Xf);
    gin_kernel<<<Nn / 16, 512, 0, stream>>>(Xf, Wih, bih, bhh, G);
    lstm_kernel<<<1, 512, 0, stream>>>(Whh, G, hsb);
    y_kernel<<<Nn / 4, 256, 0, stream>>>(hsb, wl, bl, out);
}

// Round 4
// 1554.851 us; speedup vs baseline: 1.7640x; 1.1083x over previous
//
#include <hip/hip_runtime.h>
#include <math.h>

// Problem constants
#define Nn     2048
#define NEc    32768
#define ETc    4
#define NEDGE  (ETc * NEc)     // 131072
#define FS     68              // padded feature stride (66 used)
#define HIDc   128
#define GSZ    512             // 4*HID

typedef float f4 __attribute__((ext_vector_type(4)));
typedef float f2 __attribute__((ext_vector_type(2)));

// ---------------- workspace layout (offsets in 4-byte units) ----------------
#define O_COEFF   0L
#define O_COUNTS  (O_COEFF  + 32L)
#define O_OFFS    (O_COUNTS + 2048L)
#define O_CURSOR  (O_OFFS   + 2052L)
#define O_PACKED  (O_CURSOR + 2048L)
#define O_WVAL    (O_PACKED + 131072L)              // 6 * 131072
#define O_U       (O_WVAL   + 786432L)              // 2048*68
#define O_V       (O_U      + 139264L)              // 2 ch * 2048*68
#define O_T       (O_V      + 278528L)
#define O_S       (O_T      + 278528L)
#define O_X       (O_S      + 278528L)              // 2048*128
#define O_G       (O_X      + 262144L)              // 2048*512 (gate-contig layout)
#define O_HS      (O_G      + 1048576L)             // 2048*128

// ---- softmax coefficients: coeff[(l*2+c)*4 + e] = softmax(gt_w[l][c][:])[e]
__global__ void coeff_kernel(const float* __restrict__ gtw, float* __restrict__ coeff) {
    int t = threadIdx.x;
    if (t < 6) {
        const float* w = gtw + t * 4;
        float m = fmaxf(fmaxf(w[0], w[1]), fmaxf(w[2], w[3]));
        float e0 = expf(w[0] - m), e1 = expf(w[1] - m);
        float e2 = expf(w[2] - m), e3 = expf(w[3] - m);
        float s = ((e0 + e1) + e2) + e3;
        float r = 1.0f / s;
        coeff[t * 4 + 0] = e0 * r;
        coeff[t * 4 + 1] = e1 * r;
        coeff[t * 4 + 2] = e2 * r;
        coeff[t * 4 + 3] = e3 * r;
    }
}

// ---- CSR build: count per row
__global__ void count_kernel(const int* __restrict__ ei, int* __restrict__ counts) {
    int e = blockIdx.x * 256 + threadIdx.x;          // 0..131071
    int t = e >> 15, k = e & 32767;
    int row = ei[t * 65536 + k];
    atomicAdd(&counts[row], 1);
}

// ---- exclusive scan over 2048 counts (single block, Hillis-Steele)
__global__ __launch_bounds__(1024) void scan_kernel(const int* __restrict__ counts,
                                                    int* __restrict__ offs,
                                                    int* __restrict__ cursor) {
    __shared__ int buf[2][2048];
    int t = threadIdx.x;
    buf[0][t]        = counts[t];
    buf[0][t + 1024] = counts[t + 1024];
    __syncthreads();
    int p = 0;
    for (int off = 1; off < 2048; off <<= 1) {
        for (int i = t; i < 2048; i += 1024) {
            int v = buf[p][i];
            if (i >= off) v += buf[p][i - off];
            buf[p ^ 1][i] = v;
        }
        __syncthreads();
        p ^= 1;
    }
    for (int i = t; i < 2048; i += 1024) {
        int inc = buf[p][i];
        offs[i + 1] = inc;
        int ex = inc - counts[i];
        cursor[i] = ex;
    }
    if (t == 0) offs[0] = 0;
}

// ---- scatter edges into CSR slots; pre-multiply the 6 layer/channel coeffs
__global__ void scatter_kernel(const int* __restrict__ ei, const float* __restrict__ ev,
                               const float* __restrict__ coeff,
                               int* __restrict__ cursor, int* __restrict__ packed,
                               float* __restrict__ wvals) {
    int e = blockIdx.x * 256 + threadIdx.x;
    int t = e >> 15, k = e & 32767;
    int row = ei[t * 65536 + k];
    int col = ei[t * 65536 + 32768 + k];
    float v = ev[t * 32768 + k];
    int slot = atomicAdd(&cursor[row], 1);
    packed[slot] = col;
    #pragma unroll
    for (int lc = 0; lc < 6; ++lc)
        wvals[lc * 131072L + slot] = coeff[lc * 4 + t] * v;
}

// ---- XW = X @ W_gcn, assemble U = [XW | 1 | 0 | pad]
__global__ void xw_kernel(const float* __restrict__ X, const float* __restrict__ Wg,
                          float* __restrict__ U) {
    __shared__ float Wl[64][65];
    __shared__ float Xl[16][64];
    int tid = threadIdx.x;                            // 256 threads
    for (int i = tid; i < 4096; i += 256) Wl[i >> 6][i & 63] = Wg[i];
    int r0 = blockIdx.x * 16;
    for (int i = tid; i < 1024; i += 256) Xl[i >> 6][i & 63] = X[r0 * 64 + i];
    __syncthreads();
    int lane = tid & 63, wv = tid >> 6;
    for (int rr = wv; rr < 16; rr += 4) {
        float acc = 0.0f;
        #pragma unroll
        for (int k = 0; k < 64; ++k) acc += Xl[rr][k] * Wl[k][lane];
        long r = r0 + rr;
        U[r * FS + lane] = acc;
        if (lane == 0) {
            U[r * FS + 64] = 1.0f;   // ones column (carries deg chains)
            U[r * FS + 65] = 0.0f;
            U[r * FS + 66] = 0.0f;
            U[r * FS + 67] = 0.0f;
        }
    }
}

// ---- SpMM, both channels fused: out_c[row,:] = sum_i wv_c[i] * in_c[col_i,:]
__global__ __launch_bounds__(64) void spmm_kernel(
    const int* __restrict__ offs, const int* __restrict__ packed,
    const float* __restrict__ wvals, int layer,
    const float* __restrict__ in, long in_ch_stride,
    float* __restrict__ out, long out_ch_stride, int append_one) {
    int lane = threadIdx.x;
    int row = blockIdx.x;
    const float* wv0 = wvals + (layer * 2 + 0) * 131072L;
    const float* wv1 = wvals + (layer * 2 + 1) * 131072L;
    const float* in0 = in;
    const float* in1 = in + in_ch_stride;            // == in0 when stride 0
    int s = offs[row], e = offs[row + 1];
    float acc0 = 0.0f, acc1 = 0.0f, accb0 = 0.0f, accb1 = 0.0f;
    for (int i = s; i < e; ++i) {
        long col = packed[i];
        float w0 = wv0[i], w1 = wv1[i];
        float x0 = in0[col * FS + lane];
        float x1 = in1[col * FS + lane];
        acc0 = fmaf(w0, x0, acc0);
        acc1 = fmaf(w1, x1, acc1);
        if (lane < 2) {
            accb0 = fmaf(w0, in0[col * FS + 64 + lane], accb0);
            accb1 = fmaf(w1, in1[col * FS + 64 + lane], accb1);
        }
    }
    out[(long)row * FS + lane] = acc0;
    out[out_ch_stride + (long)row * FS + lane] = acc1;
    if (lane < 2) {
        float vb0 = accb0, vb1 = accb1;
        if (append_one && lane == 1) { vb0 = 1.0f; vb1 = 1.0f; }
        out[(long)row * FS + 64 + lane] = vb0;
        out[out_ch_stride + (long)row * FS + 64 + lane] = vb1;
    }
}

// ---- finalize: X_[n, c*64+f] = relu(dinv2*dinv1*S_c[n,f] + b_gcn[f])
__global__ __launch_bounds__(128) void finalize_kernel(const float* __restrict__ S,
                                                       const float* __restrict__ bg,
                                                       float* __restrict__ Xo) {
    int n = blockIdx.x;
    int tid = threadIdx.x;                            // 128
    int c = tid >> 6, f = tid & 63;
    const float* Sc = S + (long)c * 139264L + (long)n * FS;
    float deg1 = Sc[65];
    float dinv1 = (deg1 != 0.0f) ? 1.0f / deg1 : 0.0f;
    float deg2 = dinv1 * Sc[64];
    float dinv2 = (deg2 != 0.0f) ? 1.0f / deg2 : 0.0f;
    float v = dinv2 * (dinv1 * Sc[f]) + bg[f];
    Xo[(long)n * 128 + tid] = v > 0.0f ? v : 0.0f;
}

// ---- G[n, j*4+q] = X_[n,:] . W_ih[q*128+j,:] + b_ih + b_hh   (gate-contiguous)
__global__ __launch_bounds__(512) void gin_kernel(const float* __restrict__ Xi,
                                                  const float* __restrict__ Wih,
                                                  const float* __restrict__ bih,
                                                  const float* __restrict__ bhh,
                                                  float* __restrict__ G) {
    __shared__ float Xl[16][128];
    int tid = threadIdx.x;                            // 512; W_ih row = tid
    int r0 = blockIdx.x * 16;
    for (int i = tid; i < 2048; i += 512) Xl[i >> 7][i & 127] = Xi[(long)r0 * 128 + i];
    __syncthreads();
    float acc[16];
    #pragma unroll
    for (int r = 0; r < 16; ++r) acc[r] = 0.0f;
    for (int k = 0; k < 128; ++k) {
        float w = Wih[(long)tid * 128 + k];
        #pragma unroll
        for (int r = 0; r < 16; ++r) acc[r] += Xl[r][k] * w;
    }
    float b = bih[tid] + bhh[tid];
    int col = ((tid & 127) << 2) + (tid >> 7);        // unit-major, gate-contig
    #pragma unroll
    for (int r = 0; r < 16; ++r) G[(long)(r0 + r) * GSZ + col] = acc[r] + b;
}

// ---- sequential LSTM: one block, 512 threads (8 waves).
// Lane map: wave w(0..7), lane l: ks=l>>4 (k-split 0..3), sub=l&15.
// Thread owns ALL 4 GATES of unit j=w*16+sub, k-range [ks*32, ks*32+32):
//   128 weights/thread, 32-float h chunk -> LDS traffic 64 KB/step (was 256).
// kappa-reduce: shfl_xor(16)+shfl_xor(32). No gate-gather shuffles needed.
// h double-buffered in LDS, chunk-padded (stride 36) -> conflict-free.
__global__ __launch_bounds__(512, 1) void lstm_kernel(const float* __restrict__ Whh,
                                                      const float* __restrict__ G,
                                                      float* __restrict__ hs) {
    __shared__ float h2[2][144];                      // 4 chunks * 36 floats
    int tid = threadIdx.x;
    int w = tid >> 6, l = tid & 63;
    int ks = l >> 4, sub = l & 15;
    int j = w * 16 + sub;                             // hidden unit 0..127
    int k0 = ks * 32;

    // weights: rows q*128+j, cols [k0, k0+32) as 16 float2 per gate
    f2 wv[4][16];
    #pragma unroll
    for (int q = 0; q < 4; ++q) {
        const f2* Wp = reinterpret_cast<const f2*>(Whh + (long)(q * 128 + j) * 128 + k0);
        #pragma unroll
        for (int p = 0; p < 16; ++p) wv[q][p] = Wp[p];
    }

    for (int i = tid; i < 288; i += 512) ((float*)h2)[i] = 0.0f;
    float c = 0.0f;
    const f4* Gj = reinterpret_cast<const f4*>(G + (long)(j << 2));
    f4 gcur = Gj[0];                                  // gates i,f,g,o of unit j
    __syncthreads();

    for (int t = 0; t < Nn; ++t) {
        f4 gnext;
        if (t + 1 < Nn) gnext = Gj[(long)(t + 1) << 7];
        else            gnext = (f4){0.0f, 0.0f, 0.0f, 0.0f};

        // load my 32-float h chunk (8 x b128, disjoint bank groups across ks)
        const f4* hb = reinterpret_cast<const f4*>(&h2[t & 1][ks * 36]);
        f2 a0 = {0.0f, 0.0f}, a1 = {0.0f, 0.0f}, a2 = {0.0f, 0.0f}, a3 = {0.0f, 0.0f};
        #pragma unroll
        for (int p = 0; p < 8; ++p) {
            f4 hv = hb[p];
            f2 hl = {hv.x, hv.y};
            f2 hh = {hv.z, hv.w};
            a0 += wv[0][2 * p] * hl; a0 += wv[0][2 * p + 1] * hh;
            a1 += wv[1][2 * p] * hl; a1 += wv[1][2 * p + 1] * hh;
            a2 += wv[2][2 * p] * hl; a2 += wv[2][2 * p + 1] * hh;
            a3 += wv[3][2 * p] * hl; a3 += wv[3][2 * p + 1] * hh;
        }
        float A0 = a0.x + a0.y, A1 = a1.x + a1.y;
        float A2 = a2.x + a2.y, A3 = a3.x + a3.y;
        // kappa-reduce across the 4 k-split groups (lanes l^16, l^32)
        A0 += __shfl_xor(A0, 16); A0 += __shfl_xor(A0, 32);
        A1 += __shfl_xor(A1, 16); A1 += __shfl_xor(A1, 32);
        A2 += __shfl_xor(A2, 16); A2 += __shfl_xor(A2, 32);
        A3 += __shfl_xor(A3, 16); A3 += __shfl_xor(A3, 32);
        A0 += gcur.x; A1 += gcur.y; A2 += gcur.z; A3 += gcur.w;

        float i_ = __builtin_amdgcn_rcpf(1.0f + __expf(-A0));
        float f_ = __builtin_amdgcn_rcpf(1.0f + __expf(-A1));
        float g_ = fmaf(2.0f, __builtin_amdgcn_rcpf(1.0f + __expf(-2.0f * A2)), -1.0f);
        float o_ = __builtin_amdgcn_rcpf(1.0f + __expf(-A3));
        c = fmaf(f_, c, i_ * g_);
        float th = fmaf(2.0f, __builtin_amdgcn_rcpf(1.0f + __expf(-2.0f * c)), -1.0f);
        float h = o_ * th;
        if (l < 16) {                                 // ks==0 lanes write
            h2[(t + 1) & 1][((j >> 5) * 36) + (j & 31)] = h;
            hs[(long)t * HIDc + j] = h;
        }
        gcur = gnext;
        __syncthreads();
    }
}

// ---- y[n] = leaky_relu(hs[n,:] . W_lin + b_lin)
__global__ __launch_bounds__(256) void y_kernel(const float* __restrict__ hs,
                                                const float* __restrict__ wl,
                                                const float* __restrict__ bl,
                                                float* __restrict__ out) {
    int row = blockIdx.x * 4 + (threadIdx.x >> 6);
    int lane = threadIdx.x & 63;
    float p = hs[(long)row * 128 + lane] * wl[lane] +
              hs[(long)row * 128 + 64 + lane] * wl[64 + lane];
    #pragma unroll
    for (int off = 32; off > 0; off >>= 1) p += __shfl_down(p, off);
    if (lane == 0) {
        float y = p + bl[0];
        out[row] = (y >= 0.0f) ? y : 0.2f * y;
    }
}

extern "C" void kernel_launch(void* const* d_in, const int* in_sizes, int n_in,
                              void* d_out, int out_size, void* d_ws, size_t ws_size,
                              hipStream_t stream) {
    (void)in_sizes; (void)n_in; (void)out_size; (void)ws_size;
    const int*   ei   = (const int*)  d_in[0];   // (4,2,32768)
    const float* ev   = (const float*)d_in[1];   // (4,32768)
    const float* X    = (const float*)d_in[2];   // (2048,64)
    const float* gtw  = (const float*)d_in[4];   // (3,2,4)
    const float* Wg   = (const float*)d_in[5];   // (64,64)
    const float* bg   = (const float*)d_in[6];   // (64)
    const float* Wih  = (const float*)d_in[7];   // (512,128)
    const float* Whh  = (const float*)d_in[8];   // (512,128)
    const float* bih  = (const float*)d_in[9];
    const float* bhh  = (const float*)d_in[10];
    const float* wl   = (const float*)d_in[11];  // (1,128)
    const float* bl   = (const float*)d_in[12];
    float* out = (float*)d_out;

    float* ws = (float*)d_ws;
    float* coeff  = ws + O_COEFF;
    int*   counts = (int*)(ws + O_COUNTS);
    int*   offs   = (int*)(ws + O_OFFS);
    int*   cursor = (int*)(ws + O_CURSOR);
    int*   packed = (int*)(ws + O_PACKED);
    float* wvals  = ws + O_WVAL;
    float* U      = ws + O_U;
    float* V      = ws + O_V;
    float* T      = ws + O_T;
    float* S      = ws + O_S;
    float* Xf     = ws + O_X;
    float* G      = ws + O_G;
    float* hsb    = ws + O_HS;

    hipMemsetAsync(counts, 0, 2048 * sizeof(int), stream);
    coeff_kernel<<<1, 64, 0, stream>>>(gtw, coeff);
    count_kernel<<<NEDGE / 256, 256, 0, stream>>>(ei, counts);
    scan_kernel<<<1, 1024, 0, stream>>>(counts, offs, cursor);
    scatter_kernel<<<NEDGE / 256, 256, 0, stream>>>(ei, ev, coeff, cursor, packed, wvals);
    xw_kernel<<<Nn / 16, 256, 0, stream>>>(X, Wg, U);
    // chain: V = A2 [XW|1] (append 1-col); T = A1 V; S = A0 T
    spmm_kernel<<<Nn, 64, 0, stream>>>(offs, packed, wvals, 2, U, 0L, V, 139264L, 1);
    spmm_kernel<<<Nn, 64, 0, stream>>>(offs, packed, wvals, 1, V, 139264L, T, 139264L, 0);
    spmm_kernel<<<Nn, 64, 0, stream>>>(offs, packed, wvals, 0, T, 139264L, S, 139264L, 0);
    finalize_kernel<<<Nn, 128, 0, stream>>>(S, bg, Xf);
    gin_kernel<<<Nn / 16, 512, 0, stream>>>(Xf, Wih, bih, bhh, G);
    lstm_kernel<<<1, 512, 0, stream>>>(Whh, G, hsb);
    y_kernel<<<Nn / 4, 256, 0, stream>>>(hsb, wl, bl, out);
}

// Round 5
// 1551.256 us; speedup vs baseline: 1.7681x; 1.0023x over previous
//
#include <hip/hip_runtime.h>
#include <math.h>

// Problem constants
#define Nn     2048
#define NEc    32768
#define ETc    4
#define NEDGE  (ETc * NEc)     // 131072
#define FS     68              // padded feature stride (66 used)
#define HIDc   128
#define GSZ    512             // 4*HID

typedef float f4 __attribute__((ext_vector_type(4)));
typedef float f2 __attribute__((ext_vector_type(2)));

// ---------------- workspace layout (offsets in 4-byte units) ----------------
#define O_COEFF   0L
#define O_COUNTS  (O_COEFF  + 32L)
#define O_OFFS    (O_COUNTS + 2048L)
#define O_CURSOR  (O_OFFS   + 2052L)
#define O_PACKED  (O_CURSOR + 2048L)
#define O_WVAL    (O_PACKED + 131072L)              // 6 * 131072
#define O_U       (O_WVAL   + 786432L)              // 2048*68
#define O_V       (O_U      + 139264L)              // 2 ch * 2048*68
#define O_T       (O_V      + 278528L)
#define O_S       (O_T      + 278528L)
#define O_X       (O_S      + 278528L)              // 2048*128
#define O_G       (O_X      + 262144L)              // 2048*512 (gate-contig layout)
#define O_HS      (O_G      + 1048576L)             // 2048*128

// VALU-pipe cross-lane reductions (replace DS-pipe shfl_xor).
// b=a; v_permlane16_swap_b32 b,a  => b[l],a[l] hold the {l^16} pair -> a+b.
__device__ __forceinline__ float xorsum16(float a) {
    float b = a;
    asm volatile("v_permlane16_swap_b32 %0, %1" : "+v"(b), "+v"(a));
    return a + b;
}
__device__ __forceinline__ float xorsum32(float a) {
    float b = a;
    asm volatile("v_permlane32_swap_b32 %0, %1" : "+v"(b), "+v"(a));
    return a + b;
}

// ---- softmax coefficients: coeff[(l*2+c)*4 + e] = softmax(gt_w[l][c][:])[e]
__global__ void coeff_kernel(const float* __restrict__ gtw, float* __restrict__ coeff) {
    int t = threadIdx.x;
    if (t < 6) {
        const float* w = gtw + t * 4;
        float m = fmaxf(fmaxf(w[0], w[1]), fmaxf(w[2], w[3]));
        float e0 = expf(w[0] - m), e1 = expf(w[1] - m);
        float e2 = expf(w[2] - m), e3 = expf(w[3] - m);
        float s = ((e0 + e1) + e2) + e3;
        float r = 1.0f / s;
        coeff[t * 4 + 0] = e0 * r;
        coeff[t * 4 + 1] = e1 * r;
        coeff[t * 4 + 2] = e2 * r;
        coeff[t * 4 + 3] = e3 * r;
    }
}

// ---- CSR build: count per row
__global__ void count_kernel(const int* __restrict__ ei, int* __restrict__ counts) {
    int e = blockIdx.x * 256 + threadIdx.x;          // 0..131071
    int t = e >> 15, k = e & 32767;
    int row = ei[t * 65536 + k];
    atomicAdd(&counts[row], 1);
}

// ---- exclusive scan over 2048 counts (single block, Hillis-Steele)
__global__ __launch_bounds__(1024) void scan_kernel(const int* __restrict__ counts,
                                                    int* __restrict__ offs,
                                                    int* __restrict__ cursor) {
    __shared__ int buf[2][2048];
    int t = threadIdx.x;
    buf[0][t]        = counts[t];
    buf[0][t + 1024] = counts[t + 1024];
    __syncthreads();
    int p = 0;
    for (int off = 1; off < 2048; off <<= 1) {
        for (int i = t; i < 2048; i += 1024) {
            int v = buf[p][i];
            if (i >= off) v += buf[p][i - off];
            buf[p ^ 1][i] = v;
        }
        __syncthreads();
        p ^= 1;
    }
    for (int i = t; i < 2048; i += 1024) {
        int inc = buf[p][i];
        offs[i + 1] = inc;
        int ex = inc - counts[i];
        cursor[i] = ex;
    }
    if (t == 0) offs[0] = 0;
}

// ---- scatter edges into CSR slots; pre-multiply the 6 layer/channel coeffs
__global__ void scatter_kernel(const int* __restrict__ ei, const float* __restrict__ ev,
                               const float* __restrict__ coeff,
                               int* __restrict__ cursor, int* __restrict__ packed,
                               float* __restrict__ wvals) {
    int e = blockIdx.x * 256 + threadIdx.x;
    int t = e >> 15, k = e & 32767;
    int row = ei[t * 65536 + k];
    int col = ei[t * 65536 + 32768 + k];
    float v = ev[t * 32768 + k];
    int slot = atomicAdd(&cursor[row], 1);
    packed[slot] = col;
    #pragma unroll
    for (int lc = 0; lc < 6; ++lc)
        wvals[lc * 131072L + slot] = coeff[lc * 4 + t] * v;
}

// ---- XW = X @ W_gcn, assemble U = [XW | 1 | 0 | pad]
__global__ void xw_kernel(const float* __restrict__ X, const float* __restrict__ Wg,
                          float* __restrict__ U) {
    __shared__ float Wl[64][65];
    __shared__ float Xl[16][64];
    int tid = threadIdx.x;                            // 256 threads
    for (int i = tid; i < 4096; i += 256) Wl[i >> 6][i & 63] = Wg[i];
    int r0 = blockIdx.x * 16;
    for (int i = tid; i < 1024; i += 256) Xl[i >> 6][i & 63] = X[r0 * 64 + i];
    __syncthreads();
    int lane = tid & 63, wv = tid >> 6;
    for (int rr = wv; rr < 16; rr += 4) {
        float acc = 0.0f;
        #pragma unroll
        for (int k = 0; k < 64; ++k) acc += Xl[rr][k] * Wl[k][lane];
        long r = r0 + rr;
        U[r * FS + lane] = acc;
        if (lane == 0) {
            U[r * FS + 64] = 1.0f;   // ones column (carries deg chains)
            U[r * FS + 65] = 0.0f;
            U[r * FS + 66] = 0.0f;
            U[r * FS + 67] = 0.0f;
        }
    }
}

// ---- SpMM, both channels fused: out_c[row,:] = sum_i wv_c[i] * in_c[col_i,:]
__global__ __launch_bounds__(64) void spmm_kernel(
    const int* __restrict__ offs, const int* __restrict__ packed,
    const float* __restrict__ wvals, int layer,
    const float* __restrict__ in, long in_ch_stride,
    float* __restrict__ out, long out_ch_stride, int append_one) {
    int lane = threadIdx.x;
    int row = blockIdx.x;
    const float* wv0 = wvals + (layer * 2 + 0) * 131072L;
    const float* wv1 = wvals + (layer * 2 + 1) * 131072L;
    const float* in0 = in;
    const float* in1 = in + in_ch_stride;            // == in0 when stride 0
    int s = offs[row], e = offs[row + 1];
    float acc0 = 0.0f, acc1 = 0.0f, accb0 = 0.0f, accb1 = 0.0f;
    for (int i = s; i < e; ++i) {
        long col = packed[i];
        float w0 = wv0[i], w1 = wv1[i];
        float x0 = in0[col * FS + lane];
        float x1 = in1[col * FS + lane];
        acc0 = fmaf(w0, x0, acc0);
        acc1 = fmaf(w1, x1, acc1);
        if (lane < 2) {
            accb0 = fmaf(w0, in0[col * FS + 64 + lane], accb0);
            accb1 = fmaf(w1, in1[col * FS + 64 + lane], accb1);
        }
    }
    out[(long)row * FS + lane] = acc0;
    out[out_ch_stride + (long)row * FS + lane] = acc1;
    if (lane < 2) {
        float vb0 = accb0, vb1 = accb1;
        if (append_one && lane == 1) { vb0 = 1.0f; vb1 = 1.0f; }
        out[(long)row * FS + 64 + lane] = vb0;
        out[out_ch_stride + (long)row * FS + 64 + lane] = vb1;
    }
}

// ---- finalize: X_[n, c*64+f] = relu(dinv2*dinv1*S_c[n,f] + b_gcn[f])
__global__ __launch_bounds__(128) void finalize_kernel(const float* __restrict__ S,
                                                       const float* __restrict__ bg,
                                                       float* __restrict__ Xo) {
    int n = blockIdx.x;
    int tid = threadIdx.x;                            // 128
    int c = tid >> 6, f = tid & 63;
    const float* Sc = S + (long)c * 139264L + (long)n * FS;
    float deg1 = Sc[65];
    float dinv1 = (deg1 != 0.0f) ? 1.0f / deg1 : 0.0f;
    float deg2 = dinv1 * Sc[64];
    float dinv2 = (deg2 != 0.0f) ? 1.0f / deg2 : 0.0f;
    float v = dinv2 * (dinv1 * Sc[f]) + bg[f];
    Xo[(long)n * 128 + tid] = v > 0.0f ? v : 0.0f;
}

// ---- G[n, j*4+q] = X_[n,:] . W_ih[q*128+j,:] + b_ih + b_hh   (gate-contiguous)
__global__ __launch_bounds__(512) void gin_kernel(const float* __restrict__ Xi,
                                                  const float* __restrict__ Wih,
                                                  const float* __restrict__ bih,
                                                  const float* __restrict__ bhh,
                                                  float* __restrict__ G) {
    __shared__ float Xl[16][128];
    int tid = threadIdx.x;                            // 512; W_ih row = tid
    int r0 = blockIdx.x * 16;
    for (int i = tid; i < 2048; i += 512) Xl[i >> 7][i & 127] = Xi[(long)r0 * 128 + i];
    __syncthreads();
    float acc[16];
    #pragma unroll
    for (int r = 0; r < 16; ++r) acc[r] = 0.0f;
    for (int k = 0; k < 128; ++k) {
        float w = Wih[(long)tid * 128 + k];
        #pragma unroll
        for (int r = 0; r < 16; ++r) acc[r] += Xl[r][k] * w;
    }
    float b = bih[tid] + bhh[tid];
    int col = ((tid & 127) << 2) + (tid >> 7);        // unit-major, gate-contig
    #pragma unroll
    for (int r = 0; r < 16; ++r) G[(long)(r0 + r) * GSZ + col] = acc[r] + b;
}

// ---- sequential LSTM: one block, 512 threads (8 waves).
// Lane map: wave w(0..7), lane l: ks=l>>4 (k-split 0..3), sub=l&15.
// Thread owns ALL 4 GATES of unit j=w*16+sub, k-range [ks*32, ks*32+32).
// kappa-reduce entirely on the VALU pipe (permlane16/32_swap), packed f2 FMAs.
// h double-buffered in LDS, chunk-padded (stride 36) -> conflict-free reads.
__global__ __launch_bounds__(512, 1) void lstm_kernel(const float* __restrict__ Whh,
                                                      const float* __restrict__ G,
                                                      float* __restrict__ hs) {
    __shared__ float h2[2][144];                      // 4 chunks * 36 floats
    int tid = threadIdx.x;
    int w = tid >> 6, l = tid & 63;
    int ks = l >> 4, sub = l & 15;
    int j = w * 16 + sub;                             // hidden unit 0..127
    int k0 = ks * 32;

    // weights: rows q*128+j, cols [k0, k0+32) as 16 f2 per gate
    f2 wv0[16], wv1[16], wv2[16], wv3[16];
    {
        const f2* Wp0 = reinterpret_cast<const f2*>(Whh + (long)(0 * 128 + j) * 128 + k0);
        const f2* Wp1 = reinterpret_cast<const f2*>(Whh + (long)(1 * 128 + j) * 128 + k0);
        const f2* Wp2 = reinterpret_cast<const f2*>(Whh + (long)(2 * 128 + j) * 128 + k0);
        const f2* Wp3 = reinterpret_cast<const f2*>(Whh + (long)(3 * 128 + j) * 128 + k0);
        #pragma unroll
        for (int p = 0; p < 16; ++p) {
            wv0[p] = Wp0[p]; wv1[p] = Wp1[p]; wv2[p] = Wp2[p]; wv3[p] = Wp3[p];
        }
    }

    for (int i = tid; i < 288; i += 512) ((float*)h2)[i] = 0.0f;
    float c = 0.0f;
    const f4* Gj = reinterpret_cast<const f4*>(G + (long)(j << 2));
    f4 gcur = Gj[0];                                  // gates i,f,g,o of unit j
    __syncthreads();

    for (int t = 0; t < Nn; ++t) {
        f4 gnext;
        if (t + 1 < Nn) gnext = Gj[(long)(t + 1) << 7];
        else            gnext = (f4){0.0f, 0.0f, 0.0f, 0.0f};

        // my 32-float h chunk (8 x b128; 4 distinct lines/wave, 16-lane bcast)
        const f4* hb = reinterpret_cast<const f4*>(&h2[t & 1][ks * 36]);
        f2 a0 = {0.0f, 0.0f}, a1 = {0.0f, 0.0f}, a2 = {0.0f, 0.0f}, a3 = {0.0f, 0.0f};
        #pragma unroll
        for (int p = 0; p < 8; ++p) {
            f4 hv = hb[p];
            f2 hl = {hv.x, hv.y};
            f2 hh = {hv.z, hv.w};
            a0 = __builtin_elementwise_fma(wv0[2 * p], hl, a0);
            a0 = __builtin_elementwise_fma(wv0[2 * p + 1], hh, a0);
            a1 = __builtin_elementwise_fma(wv1[2 * p], hl, a1);
            a1 = __builtin_elementwise_fma(wv1[2 * p + 1], hh, a1);
            a2 = __builtin_elementwise_fma(wv2[2 * p], hl, a2);
            a2 = __builtin_elementwise_fma(wv2[2 * p + 1], hh, a2);
            a3 = __builtin_elementwise_fma(wv3[2 * p], hl, a3);
            a3 = __builtin_elementwise_fma(wv3[2 * p + 1], hh, a3);
        }
        float A0 = a0.x + a0.y, A1 = a1.x + a1.y;
        float A2 = a2.x + a2.y, A3 = a3.x + a3.y;
        // kappa-reduce across the 4 k-split groups — VALU pipe only
        A0 = xorsum32(xorsum16(A0));
        A1 = xorsum32(xorsum16(A1));
        A2 = xorsum32(xorsum16(A2));
        A3 = xorsum32(xorsum16(A3));
        A0 += gcur.x; A1 += gcur.y; A2 += gcur.z; A3 += gcur.w;

        float i_ = __builtin_amdgcn_rcpf(1.0f + __expf(-A0));
        float f_ = __builtin_amdgcn_rcpf(1.0f + __expf(-A1));
        float g_ = fmaf(2.0f, __builtin_amdgcn_rcpf(1.0f + __expf(-2.0f * A2)), -1.0f);
        float o_ = __builtin_amdgcn_rcpf(1.0f + __expf(-A3));
        c = fmaf(f_, c, i_ * g_);
        float th = fmaf(2.0f, __builtin_amdgcn_rcpf(1.0f + __expf(-2.0f * c)), -1.0f);
        float h = o_ * th;
        if (l < 16) {                                 // ks==0 lanes write
            h2[(t + 1) & 1][((j >> 5) * 36) + (j & 31)] = h;
            hs[(long)t * HIDc + j] = h;
        }
        gcur = gnext;
        __syncthreads();
    }
}

// ---- y[n] = leaky_relu(hs[n,:] . W_lin + b_lin)
__global__ __launch_bounds__(256) void y_kernel(const float* __restrict__ hs,
                                                const float* __restrict__ wl,
                                                const float* __restrict__ bl,
                                                float* __restrict__ out) {
    int row = blockIdx.x * 4 + (threadIdx.x >> 6);
    int lane = threadIdx.x & 63;
    float p = hs[(long)row * 128 + lane] * wl[lane] +
              hs[(long)row * 128 + 64 + lane] * wl[64 + lane];
    #pragma unroll
    for (int off = 32; off > 0; off >>= 1) p += __shfl_down(p, off);
    if (lane == 0) {
        float y = p + bl[0];
        out[row] = (y >= 0.0f) ? y : 0.2f * y;
    }
}

extern "C" void kernel_launch(void* const* d_in, const int* in_sizes, int n_in,
                              void* d_out, int out_size, void* d_ws, size_t ws_size,
                              hipStream_t stream) {
    (void)in_sizes; (void)n_in; (void)out_size; (void)ws_size;
    const int*   ei   = (const int*)  d_in[0];   // (4,2,32768)
    const float* ev   = (const float*)d_in[1];   // (4,32768)
    const float* X    = (const float*)d_in[2];   // (2048,64)
    const float* gtw  = (const float*)d_in[4];   // (3,2,4)
    const float* Wg   = (const float*)d_in[5];   // (64,64)
    const float* bg   = (const float*)d_in[6];   // (64)
    const float* Wih  = (const float*)d_in[7];   // (512,128)
    const float* Whh  = (const float*)d_in[8];   // (512,128)
    const float* bih  = (const float*)d_in[9];
    const float* bhh  = (const float*)d_in[10];
    const float* wl   = (const float*)d_in[11];  // (1,128)
    const float* bl   = (const float*)d_in[12];
    float* out = (float*)d_out;

    float* ws = (float*)d_ws;
    float* coeff  = ws + O_COEFF;
    int*   counts = (int*)(ws + O_COUNTS);
    int*   offs   = (int*)(ws + O_OFFS);
    int*   cursor = (int*)(ws + O_CURSOR);
    int*   packed = (int*)(ws + O_PACKED);
    float* wvals  = ws + O_WVAL;
    float* U      = ws + O_U;
    float* V      = ws + O_V;
    float* T      = ws + O_T;
    float* S      = ws + O_S;
    float* Xf     = ws + O_X;
    float* G      = ws + O_G;
    float* hsb    = ws + O_HS;

    hipMemsetAsync(counts, 0, 2048 * sizeof(int), stream);
    coeff_kernel<<<1, 64, 0, stream>>>(gtw, coeff);
    count_kernel<<<NEDGE / 256, 256, 0, stream>>>(ei, counts);
    scan_kernel<<<1, 1024, 0, stream>>>(counts, offs, cursor);
    scatter_kernel<<<NEDGE / 256, 256, 0, stream>>>(ei, ev, coeff, cursor, packed, wvals);
    xw_kernel<<<Nn / 16, 256, 0, stream>>>(X, Wg, U);
    // chain: V = A2 [XW|1] (append 1-col); T = A1 V; S = A0 T
    spmm_kernel<<<Nn, 64, 0, stream>>>(offs, packed, wvals, 2, U, 0L, V, 139264L, 1);
    spmm_kernel<<<Nn, 64, 0, stream>>>(offs, packed, wvals, 1, V, 139264L, T, 139264L, 0);
    spmm_kernel<<<Nn, 64, 0, stream>>>(offs, packed, wvals, 0, T, 139264L, S, 139264L, 0);
    finalize_kernel<<<Nn, 128, 0, stream>>>(S, bg, Xf);
    gin_kernel<<<Nn / 16, 512, 0, stream>>>(Xf, Wih, bih, bhh, G);
    lstm_kernel<<<1, 512, 0, stream>>>(Whh, G, hsb);
    y_kernel<<<Nn / 4, 256, 0, stream>>>(hsb, wl, bl, out);
}

// Round 6
// 1535.915 us; speedup vs baseline: 1.7858x; 1.0100x over previous
//
#include <hip/hip_runtime.h>
#include <math.h>

// Problem constants
#define Nn     2048
#define NEc    32768
#define ETc    4
#define NEDGE  (ETc * NEc)     // 131072
#define FS     68              // padded feature stride (66 used)
#define HIDc   128
#define GSZ    512             // 4*HID

typedef float f4 __attribute__((ext_vector_type(4)));
typedef float f2 __attribute__((ext_vector_type(2)));

// ---------------- workspace layout (offsets in 4-byte units) ----------------
#define O_COEFF   0L
#define O_COUNTS  (O_COEFF  + 32L)
#define O_OFFS    (O_COUNTS + 2048L)
#define O_CURSOR  (O_OFFS   + 2052L)
#define O_PACKED  (O_CURSOR + 2048L)
#define O_WVAL    (O_PACKED + 131072L)              // 6 * 131072
#define O_U       (O_WVAL   + 786432L)              // 2048*68
#define O_V       (O_U      + 139264L)              // 2 ch * 2048*68
#define O_T       (O_V      + 278528L)
#define O_S       (O_T      + 278528L)
#define O_X       (O_S      + 278528L)              // 2048*128
#define O_G       (O_X      + 262144L)              // 2048*512 (gate-contig layout)
#define O_HS      (O_G      + 1048576L)             // 2048*128

// VALU-pipe cross-lane reductions (replace DS-pipe shfl_xor).
__device__ __forceinline__ float xorsum16(float a) {
    float b = a;
    asm volatile("v_permlane16_swap_b32 %0, %1" : "+v"(b), "+v"(a));
    return a + b;
}
__device__ __forceinline__ float xorsum32(float a) {
    float b = a;
    asm volatile("v_permlane32_swap_b32 %0, %1" : "+v"(b), "+v"(a));
    return a + b;
}

// ---- softmax coefficients: coeff[(l*2+c)*4 + e] = softmax(gt_w[l][c][:])[e]
__global__ void coeff_kernel(const float* __restrict__ gtw, float* __restrict__ coeff) {
    int t = threadIdx.x;
    if (t < 6) {
        const float* w = gtw + t * 4;
        float m = fmaxf(fmaxf(w[0], w[1]), fmaxf(w[2], w[3]));
        float e0 = expf(w[0] - m), e1 = expf(w[1] - m);
        float e2 = expf(w[2] - m), e3 = expf(w[3] - m);
        float s = ((e0 + e1) + e2) + e3;
        float r = 1.0f / s;
        coeff[t * 4 + 0] = e0 * r;
        coeff[t * 4 + 1] = e1 * r;
        coeff[t * 4 + 2] = e2 * r;
        coeff[t * 4 + 3] = e3 * r;
    }
}

// ---- CSR build: count per row
__global__ void count_kernel(const int* __restrict__ ei, int* __restrict__ counts) {
    int e = blockIdx.x * 256 + threadIdx.x;          // 0..131071
    int t = e >> 15, k = e & 32767;
    int row = ei[t * 65536 + k];
    atomicAdd(&counts[row], 1);
}

// ---- exclusive scan over 2048 counts (single block, Hillis-Steele)
__global__ __launch_bounds__(1024) void scan_kernel(const int* __restrict__ counts,
                                                    int* __restrict__ offs,
                                                    int* __restrict__ cursor) {
    __shared__ int buf[2][2048];
    int t = threadIdx.x;
    buf[0][t]        = counts[t];
    buf[0][t + 1024] = counts[t + 1024];
    __syncthreads();
    int p = 0;
    for (int off = 1; off < 2048; off <<= 1) {
        for (int i = t; i < 2048; i += 1024) {
            int v = buf[p][i];
            if (i >= off) v += buf[p][i - off];
            buf[p ^ 1][i] = v;
        }
        __syncthreads();
        p ^= 1;
    }
    for (int i = t; i < 2048; i += 1024) {
        int inc = buf[p][i];
        offs[i + 1] = inc;
        int ex = inc - counts[i];
        cursor[i] = ex;
    }
    if (t == 0) offs[0] = 0;
}

// ---- scatter edges into CSR slots; pre-multiply the 6 layer/channel coeffs
__global__ void scatter_kernel(const int* __restrict__ ei, const float* __restrict__ ev,
                               const float* __restrict__ coeff,
                               int* __restrict__ cursor, int* __restrict__ packed,
                               float* __restrict__ wvals) {
    int e = blockIdx.x * 256 + threadIdx.x;
    int t = e >> 15, k = e & 32767;
    int row = ei[t * 65536 + k];
    int col = ei[t * 65536 + 32768 + k];
    float v = ev[t * 32768 + k];
    int slot = atomicAdd(&cursor[row], 1);
    packed[slot] = col;
    #pragma unroll
    for (int lc = 0; lc < 6; ++lc)
        wvals[lc * 131072L + slot] = coeff[lc * 4 + t] * v;
}

// ---- XW = X @ W_gcn, assemble U = [XW | 1 | 0 | pad]
__global__ void xw_kernel(const float* __restrict__ X, const float* __restrict__ Wg,
                          float* __restrict__ U) {
    __shared__ float Wl[64][65];
    __shared__ float Xl[16][64];
    int tid = threadIdx.x;                            // 256 threads
    for (int i = tid; i < 4096; i += 256) Wl[i >> 6][i & 63] = Wg[i];
    int r0 = blockIdx.x * 16;
    for (int i = tid; i < 1024; i += 256) Xl[i >> 6][i & 63] = X[r0 * 64 + i];
    __syncthreads();
    int lane = tid & 63, wv = tid >> 6;
    for (int rr = wv; rr < 16; rr += 4) {
        float acc = 0.0f;
        #pragma unroll
        for (int k = 0; k < 64; ++k) acc += Xl[rr][k] * Wl[k][lane];
        long r = r0 + rr;
        U[r * FS + lane] = acc;
        if (lane == 0) {
            U[r * FS + 64] = 1.0f;   // ones column (carries deg chains)
            U[r * FS + 65] = 0.0f;
            U[r * FS + 66] = 0.0f;
            U[r * FS + 67] = 0.0f;
        }
    }
}

// ---- SpMM, both channels fused: out_c[row,:] = sum_i wv_c[i] * in_c[col_i,:]
__global__ __launch_bounds__(64) void spmm_kernel(
    const int* __restrict__ offs, const int* __restrict__ packed,
    const float* __restrict__ wvals, int layer,
    const float* __restrict__ in, long in_ch_stride,
    float* __restrict__ out, long out_ch_stride, int append_one) {
    int lane = threadIdx.x;
    int row = blockIdx.x;
    const float* wv0 = wvals + (layer * 2 + 0) * 131072L;
    const float* wv1 = wvals + (layer * 2 + 1) * 131072L;
    const float* in0 = in;
    const float* in1 = in + in_ch_stride;            // == in0 when stride 0
    int s = offs[row], e = offs[row + 1];
    float acc0 = 0.0f, acc1 = 0.0f, accb0 = 0.0f, accb1 = 0.0f;
    for (int i = s; i < e; ++i) {
        long col = packed[i];
        float w0 = wv0[i], w1 = wv1[i];
        float x0 = in0[col * FS + lane];
        float x1 = in1[col * FS + lane];
        acc0 = fmaf(w0, x0, acc0);
        acc1 = fmaf(w1, x1, acc1);
        if (lane < 2) {
            accb0 = fmaf(w0, in0[col * FS + 64 + lane], accb0);
            accb1 = fmaf(w1, in1[col * FS + 64 + lane], accb1);
        }
    }
    out[(long)row * FS + lane] = acc0;
    out[out_ch_stride + (long)row * FS + lane] = acc1;
    if (lane < 2) {
        float vb0 = accb0, vb1 = accb1;
        if (append_one && lane == 1) { vb0 = 1.0f; vb1 = 1.0f; }
        out[(long)row * FS + 64 + lane] = vb0;
        out[out_ch_stride + (long)row * FS + 64 + lane] = vb1;
    }
}

// ---- finalize: X_[n, c*64+f] = relu(dinv2*dinv1*S_c[n,f] + b_gcn[f])
__global__ __launch_bounds__(128) void finalize_kernel(const float* __restrict__ S,
                                                       const float* __restrict__ bg,
                                                       float* __restrict__ Xo) {
    int n = blockIdx.x;
    int tid = threadIdx.x;                            // 128
    int c = tid >> 6, f = tid & 63;
    const float* Sc = S + (long)c * 139264L + (long)n * FS;
    float deg1 = Sc[65];
    float dinv1 = (deg1 != 0.0f) ? 1.0f / deg1 : 0.0f;
    float deg2 = dinv1 * Sc[64];
    float dinv2 = (deg2 != 0.0f) ? 1.0f / deg2 : 0.0f;
    float v = dinv2 * (dinv1 * Sc[f]) + bg[f];
    Xo[(long)n * 128 + tid] = v > 0.0f ? v : 0.0f;
}

// ---- G[n, j*4+q] = X_[n,:] . W_ih[q*128+j,:] + b_ih + b_hh   (gate-contiguous)
__global__ __launch_bounds__(512) void gin_kernel(const float* __restrict__ Xi,
                                                  const float* __restrict__ Wih,
                                                  const float* __restrict__ bih,
                                                  const float* __restrict__ bhh,
                                                  float* __restrict__ G) {
    __shared__ float Xl[16][128];
    int tid = threadIdx.x;                            // 512; W_ih row = tid
    int r0 = blockIdx.x * 16;
    for (int i = tid; i < 2048; i += 512) Xl[i >> 7][i & 127] = Xi[(long)r0 * 128 + i];
    __syncthreads();
    float acc[16];
    #pragma unroll
    for (int r = 0; r < 16; ++r) acc[r] = 0.0f;
    for (int k = 0; k < 128; ++k) {
        float w = Wih[(long)tid * 128 + k];
        #pragma unroll
        for (int r = 0; r < 16; ++r) acc[r] += Xl[r][k] * w;
    }
    float b = bih[tid] + bhh[tid];
    int col = ((tid & 127) << 2) + (tid >> 7);        // unit-major, gate-contig
    #pragma unroll
    for (int r = 0; r < 16; ++r) G[(long)(r0 + r) * GSZ + col] = acc[r] + b;
}

// ---- sequential LSTM: one block, 512 threads (8 waves = exactly 2 waves/EU).
// amdgpu_waves_per_eu(2,2) tells the register allocator >2 waves/EU is
// impossible, so there is NO occupancy benefit to shrinking below 256 VGPRs --
// the 128 weight floats/thread can live in plain arch VGPRs (no AGPR homes,
// no rematerialized loads). This is the knob rounds 1-5 were missing.
__global__ __launch_bounds__(512)
__attribute__((amdgpu_waves_per_eu(2, 2)))
void lstm_kernel(const float* __restrict__ Whh,
                 const float* __restrict__ G,
                 float* __restrict__ hs) {
    __shared__ float h2[2][144];                      // 4 chunks * 36 floats
    int tid = threadIdx.x;
    int w = tid >> 6, l = tid & 63;
    int ks = l >> 4, sub = l & 15;
    int j = w * 16 + sub;                             // hidden unit 0..127
    int k0 = ks * 32;

    // weights: rows q*128+j, cols [k0, k0+32) as 16 f2 per gate
    f2 wv0[16], wv1[16], wv2[16], wv3[16];
    {
        const f2* Wp0 = reinterpret_cast<const f2*>(Whh + (long)(0 * 128 + j) * 128 + k0);
        const f2* Wp1 = reinterpret_cast<const f2*>(Whh + (long)(1 * 128 + j) * 128 + k0);
        const f2* Wp2 = reinterpret_cast<const f2*>(Whh + (long)(2 * 128 + j) * 128 + k0);
        const f2* Wp3 = reinterpret_cast<const f2*>(Whh + (long)(3 * 128 + j) * 128 + k0);
        #pragma unroll
        for (int p = 0; p < 16; ++p) {
            wv0[p] = Wp0[p]; wv1[p] = Wp1[p]; wv2[p] = Wp2[p]; wv3[p] = Wp3[p];
        }
    }

    for (int i = tid; i < 288; i += 512) ((float*)h2)[i] = 0.0f;
    float c = 0.0f;
    const f4* Gj = reinterpret_cast<const f4*>(G + (long)(j << 2));
    f4 gcur = Gj[0];                                  // gates i,f,g,o of unit j
    __syncthreads();

    for (int t = 0; t < Nn; ++t) {
        f4 gnext;
        if (t + 1 < Nn) gnext = Gj[(long)(t + 1) << 7];
        else            gnext = (f4){0.0f, 0.0f, 0.0f, 0.0f};

        // my 32-float h chunk (8 x b128; 4 distinct lines/wave, 16-lane bcast)
        const f4* hb = reinterpret_cast<const f4*>(&h2[t & 1][ks * 36]);
        f2 a0 = {0.0f, 0.0f}, a1 = {0.0f, 0.0f}, a2 = {0.0f, 0.0f}, a3 = {0.0f, 0.0f};
        #pragma unroll
        for (int p = 0; p < 8; ++p) {
            f4 hv = hb[p];
            f2 hl = {hv.x, hv.y};
            f2 hh = {hv.z, hv.w};
            a0 = __builtin_elementwise_fma(wv0[2 * p], hl, a0);
            a0 = __builtin_elementwise_fma(wv0[2 * p + 1], hh, a0);
            a1 = __builtin_elementwise_fma(wv1[2 * p], hl, a1);
            a1 = __builtin_elementwise_fma(wv1[2 * p + 1], hh, a1);
            a2 = __builtin_elementwise_fma(wv2[2 * p], hl, a2);
            a2 = __builtin_elementwise_fma(wv2[2 * p + 1], hh, a2);
            a3 = __builtin_elementwise_fma(wv3[2 * p], hl, a3);
            a3 = __builtin_elementwise_fma(wv3[2 * p + 1], hh, a3);
        }
        float A0 = a0.x + a0.y, A1 = a1.x + a1.y;
        float A2 = a2.x + a2.y, A3 = a3.x + a3.y;
        // kappa-reduce across the 4 k-split groups — VALU pipe only
        A0 = xorsum32(xorsum16(A0));
        A1 = xorsum32(xorsum16(A1));
        A2 = xorsum32(xorsum16(A2));
        A3 = xorsum32(xorsum16(A3));
        A0 += gcur.x; A1 += gcur.y; A2 += gcur.z; A3 += gcur.w;

        float i_ = __builtin_amdgcn_rcpf(1.0f + __expf(-A0));
        float f_ = __builtin_amdgcn_rcpf(1.0f + __expf(-A1));
        float g_ = fmaf(2.0f, __builtin_amdgcn_rcpf(1.0f + __expf(-2.0f * A2)), -1.0f);
        float o_ = __builtin_amdgcn_rcpf(1.0f + __expf(-A3));
        c = fmaf(f_, c, i_ * g_);
        float th = fmaf(2.0f, __builtin_amdgcn_rcpf(1.0f + __expf(-2.0f * c)), -1.0f);
        float h = o_ * th;
        if (l < 16) {                                 // ks==0 lanes write
            h2[(t + 1) & 1][((j >> 5) * 36) + (j & 31)] = h;
            hs[(long)t * HIDc + j] = h;
        }
        gcur = gnext;
        __syncthreads();
    }
}

// ---- y[n] = leaky_relu(hs[n,:] . W_lin + b_lin)
__global__ __launch_bounds__(256) void y_kernel(const float* __restrict__ hs,
                                                const float* __restrict__ wl,
                                                const float* __restrict__ bl,
                                                float* __restrict__ out) {
    int row = blockIdx.x * 4 + (threadIdx.x >> 6);
    int lane = threadIdx.x & 63;
    float p = hs[(long)row * 128 + lane] * wl[lane] +
              hs[(long)row * 128 + 64 + lane] * wl[64 + lane];
    #pragma unroll
    for (int off = 32; off > 0; off >>= 1) p += __shfl_down(p, off);
    if (lane == 0) {
        float y = p + bl[0];
        out[row] = (y >= 0.0f) ? y : 0.2f * y;
    }
}

extern "C" void kernel_launch(void* const* d_in, const int* in_sizes, int n_in,
                              void* d_out, int out_size, void* d_ws, size_t ws_size,
                              hipStream_t stream) {
    (void)in_sizes; (void)n_in; (void)out_size; (void)ws_size;
    const int*   ei   = (const int*)  d_in[0];   // (4,2,32768)
    const float* ev   = (const float*)d_in[1];   // (4,32768)
    const float* X    = (const float*)d_in[2];   // (2048,64)
    const float* gtw  = (const float*)d_in[4];   // (3,2,4)
    const float* Wg   = (const float*)d_in[5];   // (64,64)
    const float* bg   = (const float*)d_in[6];   // (64)
    const float* Wih  = (const float*)d_in[7];   // (512,128)
    const float* Whh  = (const float*)d_in[8];   // (512,128)
    const float* bih  = (const float*)d_in[9];
    const float* bhh  = (const float*)d_in[10];
    const float* wl   = (const float*)d_in[11];  // (1,128)
    const float* bl   = (const float*)d_in[12];
    float* out = (float*)d_out;

    float* ws = (float*)d_ws;
    float* coeff  = ws + O_COEFF;
    int*   counts = (int*)(ws + O_COUNTS);
    int*   offs   = (int*)(ws + O_OFFS);
    int*   cursor = (int*)(ws + O_CURSOR);
    int*   packed = (int*)(ws + O_PACKED);
    float* wvals  = ws + O_WVAL;
    float* U      = ws + O_U;
    float* V      = ws + O_V;
    float* T      = ws + O_T;
    float* S      = ws + O_S;
    float* Xf     = ws + O_X;
    float* G      = ws + O_G;
    float* hsb    = ws + O_HS;

    hipMemsetAsync(counts, 0, 2048 * sizeof(int), stream);
    coeff_kernel<<<1, 64, 0, stream>>>(gtw, coeff);
    count_kernel<<<NEDGE / 256, 256, 0, stream>>>(ei, counts);
    scan_kernel<<<1, 1024, 0, stream>>>(counts, offs, cursor);
    scatter_kernel<<<NEDGE / 256, 256, 0, stream>>>(ei, ev, coeff, cursor, packed, wvals);
    xw_kernel<<<Nn / 16, 256, 0, stream>>>(X, Wg, U);
    // chain: V = A2 [XW|1] (append 1-col); T = A1 V; S = A0 T
    spmm_kernel<<<Nn, 64, 0, stream>>>(offs, packed, wvals, 2, U, 0L, V, 139264L, 1);
    spmm_kernel<<<Nn, 64, 0, stream>>>(offs, packed, wvals, 1, V, 139264L, T, 139264L, 0);
    spmm_kernel<<<Nn, 64, 0, stream>>>(offs, packed, wvals, 0, T, 139264L, S, 139264L, 0);
    finalize_kernel<<<Nn, 128, 0, stream>>>(S, bg, Xf);
    gin_kernel<<<Nn / 16, 512, 0, stream>>>(Xf, Wih, bih, bhh, G);
    lstm_kernel<<<1, 512, 0, stream>>>(Whh, G, hsb);
    y_kernel<<<Nn / 4, 256, 0, stream>>>(hsb, wl, bl, out);
}